// Round 18
// baseline (46.683 us; speedup 1.0000x reference)
//
#include <hip/hip_runtime.h>
#include <hip/hip_bf16.h>
#include <cmath>

#define BATCH  4
#define CDIM   64
#define CK     8
#define NSEQ   4096
#define NSPLIT 8
#define NCHUNK (NSEQ / NSPLIT)        // 512 n per wave
#define NSUBS  (NCHUNK / 32)          // 16 PV subs per wave
#define LOG2E  1.4426950408889634f

typedef __attribute__((ext_vector_type(8)))  short short8;
typedef __attribute__((ext_vector_type(16))) float f32x16;

__device__ inline unsigned short f2bf(float f) {
    union { float f; unsigned u; } v; v.f = f;
    unsigned r = v.u + 0x7fff + ((v.u >> 16) & 1);   // RNE
    return (unsigned short)(r >> 16);
}
__device__ inline float bf2f(unsigned short h) {
    union { unsigned u; float f; } v; v.u = ((unsigned)h) << 16;
    return v.f;
}

// -------------------------------------------------------------------------
// Kernel 1 (frozen from round 12): fused prep. Blocks [0,512): f,g;
// blocks [512,640): h via MFMA into fragment layout h_t[b][n/16][c][n%16].
// -------------------------------------------------------------------------
__global__ __launch_bounds__(256) void prep_kernel(
    const float* __restrict__ x,  const float* __restrict__ wq,
    const float* __restrict__ wk, const float* __restrict__ wv,
    unsigned short* __restrict__ f_pair, unsigned short* __restrict__ g_pair,
    unsigned short* __restrict__ h_t)
{
    __shared__ __align__(16) float s_wq[CDIM][12];
    __shared__ __align__(16) float s_wk[CDIM][12];
    __shared__ __align__(16) unsigned short s_xt[4][32][72];

    const int t = threadIdx.x;

    if (blockIdx.x < 512) {
        #pragma unroll
        for (int u = 0; u < 2; ++u) {
            const int i = t + u * 256;
            const int k = i >> 6, c = i & 63;
            s_wq[c][k] = wq[i];
            s_wk[c][k] = wk[i];
        }
        __syncthreads();

        const int b  = blockIdx.x >> 7;
        const int n0 = (blockIdx.x & 127) * 32;
        const int nl = t >> 3;
        const int o  = t & 7;
        const int n  = n0 + nl;

        float fa[CK] = {0.f};
        float ga[CK] = {0.f};

        #pragma unroll
        for (int ci = 0; ci < 8; ++ci) {
            const int c   = 8 * o + ((ci + o) & 7);   // rotated: conflict-free
            const float xv = x[(b * CDIM + c) * NSEQ + n];

            const float4 q0 = *(const float4*)&s_wq[c][0];
            const float4 q1 = *(const float4*)&s_wq[c][4];
            fa[0] += q0.x * xv; fa[1] += q0.y * xv; fa[2] += q0.z * xv; fa[3] += q0.w * xv;
            fa[4] += q1.x * xv; fa[5] += q1.y * xv; fa[6] += q1.z * xv; fa[7] += q1.w * xv;

            const float4 k0  = *(const float4*)&s_wk[c][0];
            const float4 k1v = *(const float4*)&s_wk[c][4];
            ga[0] += k0.x * xv; ga[1] += k0.y * xv; ga[2] += k0.z * xv; ga[3] += k0.w * xv;
            ga[4] += k1v.x * xv; ga[5] += k1v.y * xv; ga[6] += k1v.z * xv; ga[7] += k1v.w * xv;
        }

        #pragma unroll
        for (int k = 0; k < CK; ++k) {
            fa[k] += __shfl_xor(fa[k], 1); fa[k] += __shfl_xor(fa[k], 2); fa[k] += __shfl_xor(fa[k], 4);
            ga[k] += __shfl_xor(ga[k], 1); ga[k] += __shfl_xor(ga[k], 2); ga[k] += __shfl_xor(ga[k], 4);
        }

        if (o == 0) {
            unsigned short buf[16];
            #pragma unroll
            for (int k = 0; k < CK; ++k) {
                buf[k]     = f2bf(fa[k]);
                buf[8 + k] = f2bf(fa[k] - bf2f(buf[k]));
            }
            uint4* dst = (uint4*)&f_pair[(size_t)(b * NSEQ + n) * 16];
            dst[0] = ((const uint4*)buf)[0];
            dst[1] = ((const uint4*)buf)[1];
        }
        if (o == 1) {
            unsigned short buf[16];
            #pragma unroll
            for (int k = 0; k < CK; ++k) {
                const float gs = ga[k] * LOG2E;
                buf[k]     = f2bf(gs);
                buf[8 + k] = f2bf(gs - bf2f(buf[k]));
            }
            uint4* dst = (uint4*)&g_pair[(size_t)(b * NSEQ + n) * 16];
            dst[0] = ((const uint4*)buf)[0];
            dst[1] = ((const uint4*)buf)[1];
        }
    } else {
        const int w    = t >> 6;
        const int lane = t & 63;
        const int hh   = lane >> 5;
        const int lm   = lane & 31;

        const int tile = (blockIdx.x - 512) * 4 + w;   // [0,512)
        const int b    = tile >> 7;
        const int n0   = (tile & 127) * 32;

        union U4 { short8 v; unsigned short us[8]; };
        U4 Avh[2][4], Avl[2][4];
        #pragma unroll
        for (int mt2 = 0; mt2 < 2; ++mt2) {
            const int row = mt2 * 32 + lm;
            #pragma unroll
            for (int kc = 0; kc < 4; ++kc) {
                const int k0 = kc * 16 + hh * 8;
                const float4 w0 = *(const float4*)&wv[row * 64 + k0];
                const float4 w1 = *(const float4*)&wv[row * 64 + k0 + 4];
                const float wf[8] = {w0.x, w0.y, w0.z, w0.w, w1.x, w1.y, w1.z, w1.w};
                #pragma unroll
                for (int j = 0; j < 8; ++j) {
                    const unsigned short hi = f2bf(wf[j]);
                    Avh[mt2][kc].us[j] = hi;
                    Avl[mt2][kc].us[j] = f2bf(wf[j] - bf2f(hi));
                }
            }
        }

        {
            const float* xs = &x[(size_t)(b * CDIM + lane) * NSEQ + n0];
            #pragma unroll
            for (int u = 0; u < 8; ++u) {
                const float4 v = *(const float4*)&xs[u * 4];
                s_xt[w][u*4 + 0][lane] = f2bf(v.x);
                s_xt[w][u*4 + 1][lane] = f2bf(v.y);
                s_xt[w][u*4 + 2][lane] = f2bf(v.z);
                s_xt[w][u*4 + 3][lane] = f2bf(v.w);
            }
        }
        __syncthreads();

        f32x16 acc0 = {}, acc1 = {};
        #pragma unroll
        for (int kc = 0; kc < 4; ++kc) {
            union U2x { short8 v; uint2 q[2]; } Bx;
            Bx.q[0] = *(const uint2*)&s_xt[w][lm][kc * 16 + hh * 8];
            Bx.q[1] = *(const uint2*)&s_xt[w][lm][kc * 16 + hh * 8 + 4];
            acc0 = __builtin_amdgcn_mfma_f32_32x32x16_bf16(Avh[0][kc].v, Bx.v, acc0, 0, 0, 0);
            acc0 = __builtin_amdgcn_mfma_f32_32x32x16_bf16(Avl[0][kc].v, Bx.v, acc0, 0, 0, 0);
            acc1 = __builtin_amdgcn_mfma_f32_32x32x16_bf16(Avh[1][kc].v, Bx.v, acc1, 0, 0, 0);
            acc1 = __builtin_amdgcn_mfma_f32_32x32x16_bf16(Avl[1][kc].v, Bx.v, acc1, 0, 0, 0);
        }

        __syncthreads();
        unsigned short* sh = &s_xt[w][0][0];
        const int nb_lo = lm >> 4, ne = lm & 15;
        #pragma unroll
        for (int r = 0; r < 16; ++r) {
            const int c0 = (r & 3) + 8 * (r >> 2) + 4 * hh;
            sh[(nb_lo * CDIM + c0)      * 16 + ne] = f2bf(acc0[r]);
            sh[(nb_lo * CDIM + 32 + c0) * 16 + ne] = f2bf(acc1[r]);
        }
        __syncthreads();
        uint4* dst = (uint4*)&h_t[(size_t)(b * (NSEQ / 16) + (n0 >> 4)) * (CDIM * 16)];
        const uint4* srcl = (const uint4*)sh;
        #pragma unroll
        for (int u = 0; u < 4; ++u)
            dst[u * 64 + lane] = srcl[u * 64 + lane];
    }
}

// -------------------------------------------------------------------------
// Kernel 2: round-13 attn, ONLY change vs R16: the main loop is unrolled
// by 2 (not fully) — j&1 stays compile-time per body (static buffer index,
// rule-#20 safe) while giving the allocator a rotating loop decoupled from
// the epilogue, instead of one 16-body mega-region.
// -------------------------------------------------------------------------
__global__ __launch_bounds__(512, 4) void attn_kernel(
    const unsigned short* __restrict__ f_pair,
    const unsigned short* __restrict__ g_pair,
    const unsigned short* __restrict__ h_t,
    const float* __restrict__ x, const float* __restrict__ gamma,
    float* __restrict__ out)
{
    __shared__ __align__(16) float s_o[CDIM][36];   // padded rows (144B)
    __shared__ __align__(16) float s_l[32];

    const int t    = threadIdx.x;
    const int w    = t >> 6;             // wave = n-split s
    const int lane = t & 63;
    const int hh   = lane >> 5;
    const int lm   = lane & 31;

    const int bid = blockIdx.x;          // 512 = b(4) * mt(128)
    const int mt  = bid & 127;
    const int b   = bid >> 7;
    const int s   = w;

    const int m = mt * 32 + lm;

    union U4 { short8 v; uint4 q4; unsigned u[4]; unsigned short us[8]; };

    U4 Bgh, Bgl;
    {
        const uint4* gp = (const uint4*)&g_pair[(size_t)(b * NSEQ + m) * 16];
        Bgh.q4 = gp[0];
        Bgl.q4 = gp[1];
    }

    f32x16 acc0 = {}, acc1 = {};
    float lsA = 0.f, lsB = 0.f;

    const unsigned short* fp = f_pair + (size_t)b * NSEQ * 16
                             + (size_t)lm * 16 + hh * 8;
    const unsigned short* ht = h_t + (size_t)(b * (NSEQ / 16) + s * (NCHUNK / 16)) * (CDIM * 16)
                             + hh * 8;

    auto loadAf = [&](int j) -> short8 {
        return *(const short8*)&fp[(size_t)(s * NCHUNK + j * 32) * 16];
    };
    auto loadH = [&](int j, uint4 (&ha)[2], uint4 (&hb2)[2]) {
        #pragma unroll
        for (int ks = 0; ks < 2; ++ks) {
            ha[ks]  = *(const uint4*)&ht[(size_t)((j * 2 + ks) * CDIM + lm) * 16];
            hb2[ks] = *(const uint4*)&ht[(size_t)((j * 2 + ks) * CDIM + 32 + lm) * 16];
        }
    };

    short8 af[2];
    uint4  hA[2][2], hB[2][2];

    af[0] = loadAf(0); loadH(0, hA[0], hB[0]);
    af[1] = loadAf(1); loadH(1, hA[1], hB[1]);

    #pragma unroll 2
    for (int j = 0; j < NSUBS; ++j) {
        const int cur = j & 1;           // static per unrolled body (unroll=2)

        const f32x16 kZ = {};
        f32x16 sc = __builtin_amdgcn_mfma_f32_32x32x16_bf16(af[cur], Bgh.v, kZ, 0, 0, 0);
        sc = __builtin_amdgcn_mfma_f32_32x32x16_bf16(af[cur], Bgl.v, sc, 0, 0, 0);

        if (j + 2 < NSUBS) af[cur] = loadAf(j + 2);

        unsigned a[8];
        #pragma unroll
        for (int p = 0; p < 8; ++p) {
            const float e0 = __builtin_amdgcn_exp2f(sc[2*p]);
            const float e1 = __builtin_amdgcn_exp2f(sc[2*p+1]);
            lsA += e0; lsB += e1;
            __hip_bfloat162 h2 = __float22bfloat162_rn(make_float2(e0, e1));
            a[p] = *(unsigned*)&h2;
        }
        const auto s02 = __builtin_amdgcn_permlane32_swap(a[0], a[2], false, false);
        const auto s13 = __builtin_amdgcn_permlane32_swap(a[1], a[3], false, false);
        const auto s46 = __builtin_amdgcn_permlane32_swap(a[4], a[6], false, false);
        const auto s57 = __builtin_amdgcn_permlane32_swap(a[5], a[7], false, false);

        U4 P0, P1;
        P0.u[0] = s02[0]; P0.u[1] = s13[0]; P0.u[2] = s02[1]; P0.u[3] = s13[1];
        P1.u[0] = s46[0]; P1.u[1] = s57[0]; P1.u[2] = s46[1]; P1.u[3] = s57[1];

        union U2x { short8 v; uint4 q; } Ax;
        __builtin_amdgcn_s_setprio(1);
        Ax.q = hA[cur][0];
        acc0 = __builtin_amdgcn_mfma_f32_32x32x16_bf16(Ax.v, P0.v, acc0, 0, 0, 0);
        Ax.q = hB[cur][0];
        acc1 = __builtin_amdgcn_mfma_f32_32x32x16_bf16(Ax.v, P0.v, acc1, 0, 0, 0);
        Ax.q = hA[cur][1];
        acc0 = __builtin_amdgcn_mfma_f32_32x32x16_bf16(Ax.v, P1.v, acc0, 0, 0, 0);
        Ax.q = hB[cur][1];
        acc1 = __builtin_amdgcn_mfma_f32_32x32x16_bf16(Ax.v, P1.v, acc1, 0, 0, 0);
        __builtin_amdgcn_s_setprio(0);

        if (j + 2 < NSUBS) loadH(j + 2, hA[cur], hB[cur]);
    }

    const float lsum = lsA + lsB;
    const float ltot = lsum + __shfl_xor(lsum, 32);

    // ---- 8-phase in-block fp32 reduction of (o, l) across the 8 waves ----
    #pragma unroll
    for (int ws = 0; ws < NSPLIT; ++ws) {
        if (w == ws) {
            if (ws == 0) {
                #pragma unroll
                for (int r = 0; r < 16; ++r) {
                    const int c0 = (r & 3) + 8 * (r >> 2) + 4 * hh;
                    s_o[c0][lm]      = acc0[r];
                    s_o[32 + c0][lm] = acc1[r];
                }
                if (hh == 0) s_l[lm] = ltot;
            } else {
                #pragma unroll
                for (int r = 0; r < 16; ++r) {
                    const int c0 = (r & 3) + 8 * (r >> 2) + 4 * hh;
                    s_o[c0][lm]      += acc0[r];
                    s_o[32 + c0][lm] += acc1[r];
                }
                if (hh == 0) s_l[lm] += ltot;
            }
        }
        __syncthreads();
    }

    // ---- epilogue: out = gamma * o / l + x (coalesced float4) ----
    {
        const float g  = gamma[0];
        const int   c  = t >> 3;            // 0..63
        const int   mg = (t & 7) * 4;       // 0,4,..,28
        const float4 ov = *(const float4*)&s_o[c][mg];
        const float4 lv = *(const float4*)&s_l[mg];
        const size_t idx = (size_t)(b * CDIM + c) * NSEQ + mt * 32 + mg;
        const float4 xv = *(const float4*)&x[idx];
        float4 r;
        r.x = g * ov.x / lv.x + xv.x;
        r.y = g * ov.y / lv.y + xv.y;
        r.z = g * ov.z / lv.z + xv.z;
        r.w = g * ov.w / lv.w + xv.w;
        *(float4*)&out[idx] = r;
    }
}

extern "C" void kernel_launch(void* const* d_in, const int* in_sizes, int n_in,
                              void* d_out, int out_size, void* d_ws, size_t ws_size,
                              hipStream_t stream) {
    const float* x     = (const float*)d_in[0];
    const float* wq    = (const float*)d_in[1];
    const float* wk    = (const float*)d_in[2];
    const float* wv    = (const float*)d_in[3];
    const float* gamma = (const float*)d_in[4];
    float* out = (float*)d_out;

    char* wsb = (char*)d_ws;
    unsigned short* f_pair = (unsigned short*)wsb;                         // 512 KB
    unsigned short* g_pair = f_pair + (size_t)BATCH * NSEQ * 16;           // 512 KB
    unsigned short* h_t    = g_pair + (size_t)BATCH * NSEQ * 16;           // 2 MB

    hipLaunchKernelGGL(prep_kernel, dim3(640), dim3(256), 0, stream,
                       x, wq, wk, wv, f_pair, g_pair, h_t);
    hipLaunchKernelGGL(attn_kernel, dim3(BATCH * 128), dim3(512), 0, stream,
                       f_pair, g_pair, h_t, x, gamma, out);
}

// Round 19
// 35.971 us; speedup vs baseline: 1.2978x; 1.2978x over previous
//
#include <hip/hip_runtime.h>
#include <hip/hip_bf16.h>
#include <cmath>

#define BATCH  4
#define CDIM   64
#define CK     8
#define NSEQ   4096
#define NSPLIT 8
#define NCHUNK (NSEQ / NSPLIT)        // 512 n per wave
#define NSUBS  (NCHUNK / 32)          // 16 PV subs per wave
#define LOG2E  1.4426950408889634f

typedef __attribute__((ext_vector_type(8)))  short short8;
typedef __attribute__((ext_vector_type(16))) float f32x16;

__device__ inline unsigned short f2bf(float f) {
    union { float f; unsigned u; } v; v.f = f;
    unsigned r = v.u + 0x7fff + ((v.u >> 16) & 1);   // RNE
    return (unsigned short)(r >> 16);
}
__device__ inline float bf2f(unsigned short h) {
    union { unsigned u; float f; } v; v.u = ((unsigned)h) << 16;
    return v.f;
}

// -------------------------------------------------------------------------
// Kernel 1 (frozen from round 12): fused prep. Blocks [0,512): f,g;
// blocks [512,640): h via MFMA into fragment layout h_t[b][n/16][c][n%16].
// -------------------------------------------------------------------------
__global__ __launch_bounds__(256) void prep_kernel(
    const float* __restrict__ x,  const float* __restrict__ wq,
    const float* __restrict__ wk, const float* __restrict__ wv,
    unsigned short* __restrict__ f_pair, unsigned short* __restrict__ g_pair,
    unsigned short* __restrict__ h_t)
{
    __shared__ __align__(16) float s_wq[CDIM][12];
    __shared__ __align__(16) float s_wk[CDIM][12];
    __shared__ __align__(16) unsigned short s_xt[4][32][72];

    const int t = threadIdx.x;

    if (blockIdx.x < 512) {
        #pragma unroll
        for (int u = 0; u < 2; ++u) {
            const int i = t + u * 256;
            const int k = i >> 6, c = i & 63;
            s_wq[c][k] = wq[i];
            s_wk[c][k] = wk[i];
        }
        __syncthreads();

        const int b  = blockIdx.x >> 7;
        const int n0 = (blockIdx.x & 127) * 32;
        const int nl = t >> 3;
        const int o  = t & 7;
        const int n  = n0 + nl;

        float fa[CK] = {0.f};
        float ga[CK] = {0.f};

        #pragma unroll
        for (int ci = 0; ci < 8; ++ci) {
            const int c   = 8 * o + ((ci + o) & 7);   // rotated: conflict-free
            const float xv = x[(b * CDIM + c) * NSEQ + n];

            const float4 q0 = *(const float4*)&s_wq[c][0];
            const float4 q1 = *(const float4*)&s_wq[c][4];
            fa[0] += q0.x * xv; fa[1] += q0.y * xv; fa[2] += q0.z * xv; fa[3] += q0.w * xv;
            fa[4] += q1.x * xv; fa[5] += q1.y * xv; fa[6] += q1.z * xv; fa[7] += q1.w * xv;

            const float4 k0  = *(const float4*)&s_wk[c][0];
            const float4 k1v = *(const float4*)&s_wk[c][4];
            ga[0] += k0.x * xv; ga[1] += k0.y * xv; ga[2] += k0.z * xv; ga[3] += k0.w * xv;
            ga[4] += k1v.x * xv; ga[5] += k1v.y * xv; ga[6] += k1v.z * xv; ga[7] += k1v.w * xv;
        }

        #pragma unroll
        for (int k = 0; k < CK; ++k) {
            fa[k] += __shfl_xor(fa[k], 1); fa[k] += __shfl_xor(fa[k], 2); fa[k] += __shfl_xor(fa[k], 4);
            ga[k] += __shfl_xor(ga[k], 1); ga[k] += __shfl_xor(ga[k], 2); ga[k] += __shfl_xor(ga[k], 4);
        }

        if (o == 0) {
            unsigned short buf[16];
            #pragma unroll
            for (int k = 0; k < CK; ++k) {
                buf[k]     = f2bf(fa[k]);
                buf[8 + k] = f2bf(fa[k] - bf2f(buf[k]));
            }
            uint4* dst = (uint4*)&f_pair[(size_t)(b * NSEQ + n) * 16];
            dst[0] = ((const uint4*)buf)[0];
            dst[1] = ((const uint4*)buf)[1];
        }
        if (o == 1) {
            unsigned short buf[16];
            #pragma unroll
            for (int k = 0; k < CK; ++k) {
                const float gs = ga[k] * LOG2E;
                buf[k]     = f2bf(gs);
                buf[8 + k] = f2bf(gs - bf2f(buf[k]));
            }
            uint4* dst = (uint4*)&g_pair[(size_t)(b * NSEQ + n) * 16];
            dst[0] = ((const uint4*)buf)[0];
            dst[1] = ((const uint4*)buf)[1];
        }
    } else {
        const int w    = t >> 6;
        const int lane = t & 63;
        const int hh   = lane >> 5;
        const int lm   = lane & 31;

        const int tile = (blockIdx.x - 512) * 4 + w;   // [0,512)
        const int b    = tile >> 7;
        const int n0   = (tile & 127) * 32;

        union U4 { short8 v; unsigned short us[8]; };
        U4 Avh[2][4], Avl[2][4];
        #pragma unroll
        for (int mt2 = 0; mt2 < 2; ++mt2) {
            const int row = mt2 * 32 + lm;
            #pragma unroll
            for (int kc = 0; kc < 4; ++kc) {
                const int k0 = kc * 16 + hh * 8;
                const float4 w0 = *(const float4*)&wv[row * 64 + k0];
                const float4 w1 = *(const float4*)&wv[row * 64 + k0 + 4];
                const float wf[8] = {w0.x, w0.y, w0.z, w0.w, w1.x, w1.y, w1.z, w1.w};
                #pragma unroll
                for (int j = 0; j < 8; ++j) {
                    const unsigned short hi = f2bf(wf[j]);
                    Avh[mt2][kc].us[j] = hi;
                    Avl[mt2][kc].us[j] = f2bf(wf[j] - bf2f(hi));
                }
            }
        }

        {
            const float* xs = &x[(size_t)(b * CDIM + lane) * NSEQ + n0];
            #pragma unroll
            for (int u = 0; u < 8; ++u) {
                const float4 v = *(const float4*)&xs[u * 4];
                s_xt[w][u*4 + 0][lane] = f2bf(v.x);
                s_xt[w][u*4 + 1][lane] = f2bf(v.y);
                s_xt[w][u*4 + 2][lane] = f2bf(v.z);
                s_xt[w][u*4 + 3][lane] = f2bf(v.w);
            }
        }
        __syncthreads();

        f32x16 acc0 = {}, acc1 = {};
        #pragma unroll
        for (int kc = 0; kc < 4; ++kc) {
            union U2x { short8 v; uint2 q[2]; } Bx;
            Bx.q[0] = *(const uint2*)&s_xt[w][lm][kc * 16 + hh * 8];
            Bx.q[1] = *(const uint2*)&s_xt[w][lm][kc * 16 + hh * 8 + 4];
            acc0 = __builtin_amdgcn_mfma_f32_32x32x16_bf16(Avh[0][kc].v, Bx.v, acc0, 0, 0, 0);
            acc0 = __builtin_amdgcn_mfma_f32_32x32x16_bf16(Avl[0][kc].v, Bx.v, acc0, 0, 0, 0);
            acc1 = __builtin_amdgcn_mfma_f32_32x32x16_bf16(Avh[1][kc].v, Bx.v, acc1, 0, 0, 0);
            acc1 = __builtin_amdgcn_mfma_f32_32x32x16_bf16(Avl[1][kc].v, Bx.v, acc1, 0, 0, 0);
        }

        __syncthreads();
        unsigned short* sh = &s_xt[w][0][0];
        const int nb_lo = lm >> 4, ne = lm & 15;
        #pragma unroll
        for (int r = 0; r < 16; ++r) {
            const int c0 = (r & 3) + 8 * (r >> 2) + 4 * hh;
            sh[(nb_lo * CDIM + c0)      * 16 + ne] = f2bf(acc0[r]);
            sh[(nb_lo * CDIM + 32 + c0) * 16 + ne] = f2bf(acc1[r]);
        }
        __syncthreads();
        uint4* dst = (uint4*)&h_t[(size_t)(b * (NSEQ / 16) + (n0 >> 4)) * (CDIM * 16)];
        const uint4* srcl = (const uint4*)sh;
        #pragma unroll
        for (int u = 0; u < 4; ++u)
            dst[u * 64 + lane] = srcl[u * 64 + lane];
    }
}

// -------------------------------------------------------------------------
// Kernel 2: fused flash attention + epilogue — FINAL, byte-exact round-13
// state (twice reproduced at 36.0/36.4 µs). MT=32, 512 blocks x 512 thr,
// (512,4), full unroll, 2 accs, 8-phase serial LDS reduction.
// DO NOT PERTURB: R14 (4 accs), R15 (atomic epilogue), R18 (unroll 2) each
// broke the register-allocation equilibrium and regressed 1.3-1.9x.
// -------------------------------------------------------------------------
__global__ __launch_bounds__(512, 4) void attn_kernel(
    const unsigned short* __restrict__ f_pair,
    const unsigned short* __restrict__ g_pair,
    const unsigned short* __restrict__ h_t,
    const float* __restrict__ x, const float* __restrict__ gamma,
    float* __restrict__ out)
{
    __shared__ __align__(16) float s_o[CDIM][36];   // padded rows (144B)
    __shared__ __align__(16) float s_l[32];

    const int t    = threadIdx.x;
    const int w    = t >> 6;             // wave = n-split s
    const int lane = t & 63;
    const int hh   = lane >> 5;
    const int lm   = lane & 31;

    const int bid = blockIdx.x;          // 512 = b(4) * mt(128)
    const int mt  = bid & 127;
    const int b   = bid >> 7;
    const int s   = w;

    const int m = mt * 32 + lm;

    union U4 { short8 v; uint4 q4; unsigned u[4]; unsigned short us[8]; };

    U4 Bgh, Bgl;
    {
        const uint4* gp = (const uint4*)&g_pair[(size_t)(b * NSEQ + m) * 16];
        Bgh.q4 = gp[0];
        Bgl.q4 = gp[1];
    }

    f32x16 acc0 = {}, acc1 = {};
    float lsA = 0.f, lsB = 0.f;

    const unsigned short* fp = f_pair + (size_t)b * NSEQ * 16
                             + (size_t)lm * 16 + hh * 8;
    const unsigned short* ht = h_t + (size_t)(b * (NSEQ / 16) + s * (NCHUNK / 16)) * (CDIM * 16)
                             + hh * 8;

    auto loadAf = [&](int j) -> short8 {
        return *(const short8*)&fp[(size_t)(s * NCHUNK + j * 32) * 16];
    };
    auto loadH = [&](int j, uint4 (&ha)[2], uint4 (&hb2)[2]) {
        #pragma unroll
        for (int ks = 0; ks < 2; ++ks) {
            ha[ks]  = *(const uint4*)&ht[(size_t)((j * 2 + ks) * CDIM + lm) * 16];
            hb2[ks] = *(const uint4*)&ht[(size_t)((j * 2 + ks) * CDIM + 32 + lm) * 16];
        }
    };

    short8 af[2];
    uint4  hA[2][2], hB[2][2];

    af[0] = loadAf(0); loadH(0, hA[0], hB[0]);
    af[1] = loadAf(1); loadH(1, hA[1], hB[1]);

    #pragma unroll
    for (int j = 0; j < NSUBS; ++j) {
        const int cur = j & 1;

        const f32x16 kZ = {};
        f32x16 sc = __builtin_amdgcn_mfma_f32_32x32x16_bf16(af[cur], Bgh.v, kZ, 0, 0, 0);
        sc = __builtin_amdgcn_mfma_f32_32x32x16_bf16(af[cur], Bgl.v, sc, 0, 0, 0);

        if (j + 2 < NSUBS) af[cur] = loadAf(j + 2);

        unsigned a[8];
        #pragma unroll
        for (int p = 0; p < 8; ++p) {
            const float e0 = __builtin_amdgcn_exp2f(sc[2*p]);
            const float e1 = __builtin_amdgcn_exp2f(sc[2*p+1]);
            lsA += e0; lsB += e1;
            __hip_bfloat162 h2 = __float22bfloat162_rn(make_float2(e0, e1));
            a[p] = *(unsigned*)&h2;
        }
        const auto s02 = __builtin_amdgcn_permlane32_swap(a[0], a[2], false, false);
        const auto s13 = __builtin_amdgcn_permlane32_swap(a[1], a[3], false, false);
        const auto s46 = __builtin_amdgcn_permlane32_swap(a[4], a[6], false, false);
        const auto s57 = __builtin_amdgcn_permlane32_swap(a[5], a[7], false, false);

        U4 P0, P1;
        P0.u[0] = s02[0]; P0.u[1] = s13[0]; P0.u[2] = s02[1]; P0.u[3] = s13[1];
        P1.u[0] = s46[0]; P1.u[1] = s57[0]; P1.u[2] = s46[1]; P1.u[3] = s57[1];

        union U2x { short8 v; uint4 q; } Ax;
        __builtin_amdgcn_s_setprio(1);
        Ax.q = hA[cur][0];
        acc0 = __builtin_amdgcn_mfma_f32_32x32x16_bf16(Ax.v, P0.v, acc0, 0, 0, 0);
        Ax.q = hB[cur][0];
        acc1 = __builtin_amdgcn_mfma_f32_32x32x16_bf16(Ax.v, P0.v, acc1, 0, 0, 0);
        Ax.q = hA[cur][1];
        acc0 = __builtin_amdgcn_mfma_f32_32x32x16_bf16(Ax.v, P1.v, acc0, 0, 0, 0);
        Ax.q = hB[cur][1];
        acc1 = __builtin_amdgcn_mfma_f32_32x32x16_bf16(Ax.v, P1.v, acc1, 0, 0, 0);
        __builtin_amdgcn_s_setprio(0);

        if (j + 2 < NSUBS) loadH(j + 2, hA[cur], hB[cur]);
    }

    const float lsum = lsA + lsB;
    const float ltot = lsum + __shfl_xor(lsum, 32);

    // ---- 8-phase in-block fp32 reduction of (o, l) across the 8 waves ----
    #pragma unroll
    for (int ws = 0; ws < NSPLIT; ++ws) {
        if (w == ws) {
            if (ws == 0) {
                #pragma unroll
                for (int r = 0; r < 16; ++r) {
                    const int c0 = (r & 3) + 8 * (r >> 2) + 4 * hh;
                    s_o[c0][lm]      = acc0[r];
                    s_o[32 + c0][lm] = acc1[r];
                }
                if (hh == 0) s_l[lm] = ltot;
            } else {
                #pragma unroll
                for (int r = 0; r < 16; ++r) {
                    const int c0 = (r & 3) + 8 * (r >> 2) + 4 * hh;
                    s_o[c0][lm]      += acc0[r];
                    s_o[32 + c0][lm] += acc1[r];
                }
                if (hh == 0) s_l[lm] += ltot;
            }
        }
        __syncthreads();
    }

    // ---- epilogue: out = gamma * o / l + x (coalesced float4) ----
    {
        const float g  = gamma[0];
        const int   c  = t >> 3;            // 0..63
        const int   mg = (t & 7) * 4;       // 0,4,..,28
        const float4 ov = *(const float4*)&s_o[c][mg];
        const float4 lv = *(const float4*)&s_l[mg];
        const size_t idx = (size_t)(b * CDIM + c) * NSEQ + mt * 32 + mg;
        const float4 xv = *(const float4*)&x[idx];
        float4 r;
        r.x = g * ov.x / lv.x + xv.x;
        r.y = g * ov.y / lv.y + xv.y;
        r.z = g * ov.z / lv.z + xv.z;
        r.w = g * ov.w / lv.w + xv.w;
        *(float4*)&out[idx] = r;
    }
}

extern "C" void kernel_launch(void* const* d_in, const int* in_sizes, int n_in,
                              void* d_out, int out_size, void* d_ws, size_t ws_size,
                              hipStream_t stream) {
    const float* x     = (const float*)d_in[0];
    const float* wq    = (const float*)d_in[1];
    const float* wk    = (const float*)d_in[2];
    const float* wv    = (const float*)d_in[3];
    const float* gamma = (const float*)d_in[4];
    float* out = (float*)d_out;

    char* wsb = (char*)d_ws;
    unsigned short* f_pair = (unsigned short*)wsb;                         // 512 KB
    unsigned short* g_pair = f_pair + (size_t)BATCH * NSEQ * 16;           // 512 KB
    unsigned short* h_t    = g_pair + (size_t)BATCH * NSEQ * 16;           // 2 MB

    hipLaunchKernelGGL(prep_kernel, dim3(640), dim3(256), 0, stream,
                       x, wq, wk, wv, f_pair, g_pair, h_t);
    hipLaunchKernelGGL(attn_kernel, dim3(BATCH * 128), dim3(512), 0, stream,
                       f_pair, g_pair, h_t, x, gamma, out);
}